// Round 1
// baseline (1173.406 us; speedup 1.0000x reference)
//
#include <hip/hip_runtime.h>

typedef _Float16 half8 __attribute__((ext_vector_type(8)));
typedef float floatx4 __attribute__((ext_vector_type(4)));

// LDS layout helper: rows of 32 fp16 (one BK=32 slice), 4 chunks of 8, XOR-swizzled
// so ds_read_b128 fragment reads are ~conflict-free.
__device__ __forceinline__ int lds_off(int row, int chunk) {
    return row * 32 + ((chunk ^ (row & 3)) << 3);
}

// C = A @ B^T (both row-major [rows, K]) with optional fp32->fp16 conversion during
// staging. 128x128 tile, 4 waves, BK=32, mfma_f32_16x16x32_f16.
// OUT_MODE 0: fp16 head-split [bh][l][d]   (QK projection)
// OUT_MODE 1: fp16 head-split transposed [bh][d][l]  (V projection)
// OUT_MODE 2: fp32 row-major ldc=1024 (+bias)        (output projection)
// OUT_MODE 3: fp32 row-major ldc=2048, batched by z  (scores)
template<bool A_F32, bool B_F32, int OUT_MODE>
__global__ __launch_bounds__(256) void gemm128(
    const void* __restrict__ Ap, int lda, long sAz,
    const void* __restrict__ Bp, int ldb, long sBz,
    const float* __restrict__ bias, float scale,
    void* __restrict__ Cp, long sCz, int K)
{
    __shared__ __align__(16) _Float16 sA[128 * 32];
    __shared__ __align__(16) _Float16 sB[128 * 32];

    const int t = threadIdx.x;
    const int tileN = blockIdx.x * 128;
    const int tileM = blockIdx.y * 128;
    const int z = blockIdx.z;

    const int srow = t >> 1, shalf = t & 1, c0 = shalf * 2;
    const int lane = t & 63, wave = t >> 6;
    const int wm = (wave >> 1) * 64, wn = (wave & 1) * 64;
    const int l15 = lane & 15, quad = lane >> 4;

    const char* Abase = (const char*)Ap + (long)z * sAz * (A_F32 ? 4 : 2);
    const char* Bbase = (const char*)Bp + (long)z * sBz * (B_F32 ? 4 : 2);

    floatx4 acc[4][4];
#pragma unroll
    for (int i = 0; i < 4; i++)
#pragma unroll
        for (int j = 0; j < 4; j++)
            acc[i][j] = (floatx4){0.f, 0.f, 0.f, 0.f};

    for (int k0 = 0; k0 < K; k0 += 32) {
        __syncthreads();
        // ---- stage A tile (128 x 32) ----
        if constexpr (A_F32) {
            const float* src = (const float*)Abase + (long)(tileM + srow) * lda + k0 + shalf * 16;
            float fx[16];
            *(float4*)(fx + 0)  = *(const float4*)(src + 0);
            *(float4*)(fx + 4)  = *(const float4*)(src + 4);
            *(float4*)(fx + 8)  = *(const float4*)(src + 8);
            *(float4*)(fx + 12) = *(const float4*)(src + 12);
            half8 h0, h1;
#pragma unroll
            for (int i = 0; i < 8; i++) { h0[i] = (_Float16)fx[i]; h1[i] = (_Float16)fx[8 + i]; }
            *(half8*)&sA[lds_off(srow, c0)]     = h0;
            *(half8*)&sA[lds_off(srow, c0 + 1)] = h1;
        } else {
            const _Float16* src = (const _Float16*)Abase + (long)(tileM + srow) * lda + k0 + shalf * 16;
            *(half8*)&sA[lds_off(srow, c0)]     = *(const half8*)(src);
            *(half8*)&sA[lds_off(srow, c0 + 1)] = *(const half8*)(src + 8);
        }
        // ---- stage B tile (128 x 32) ----
        if constexpr (B_F32) {
            const float* src = (const float*)Bbase + (long)(tileN + srow) * ldb + k0 + shalf * 16;
            float fx[16];
            *(float4*)(fx + 0)  = *(const float4*)(src + 0);
            *(float4*)(fx + 4)  = *(const float4*)(src + 4);
            *(float4*)(fx + 8)  = *(const float4*)(src + 8);
            *(float4*)(fx + 12) = *(const float4*)(src + 12);
            half8 h0, h1;
#pragma unroll
            for (int i = 0; i < 8; i++) { h0[i] = (_Float16)fx[i]; h1[i] = (_Float16)fx[8 + i]; }
            *(half8*)&sB[lds_off(srow, c0)]     = h0;
            *(half8*)&sB[lds_off(srow, c0 + 1)] = h1;
        } else {
            const _Float16* src = (const _Float16*)Bbase + (long)(tileN + srow) * ldb + k0 + shalf * 16;
            *(half8*)&sB[lds_off(srow, c0)]     = *(const half8*)(src);
            *(half8*)&sB[lds_off(srow, c0 + 1)] = *(const half8*)(src + 8);
        }
        __syncthreads();

        half8 af[4], bf[4];
#pragma unroll
        for (int i = 0; i < 4; i++) af[i] = *(const half8*)&sA[lds_off(wm + i * 16 + l15, quad)];
#pragma unroll
        for (int j = 0; j < 4; j++) bf[j] = *(const half8*)&sB[lds_off(wn + j * 16 + l15, quad)];
#pragma unroll
        for (int i = 0; i < 4; i++)
#pragma unroll
            for (int j = 0; j < 4; j++)
                acc[i][j] = __builtin_amdgcn_mfma_f32_16x16x32_f16(af[i], bf[j], acc[i][j], 0, 0, 0);
    }

    // ---- epilogue ----
#pragma unroll
    for (int i = 0; i < 4; i++) {
#pragma unroll
        for (int j = 0; j < 4; j++) {
#pragma unroll
            for (int r = 0; r < 4; r++) {
                const int row = tileM + wm + i * 16 + quad * 4 + r;
                const int col = tileN + wn + j * 16 + l15;
                float v = acc[i][j][r] * scale;
                if (bias) v += bias[col];
                if constexpr (OUT_MODE == 0) {
                    _Float16* dst = (_Float16*)Cp;
                    dst[(long)(((row >> 11) << 4) + (col >> 6)) * 131072 + (long)(row & 2047) * 64 + (col & 63)] = (_Float16)v;
                } else if constexpr (OUT_MODE == 1) {
                    _Float16* dst = (_Float16*)Cp;
                    dst[(long)(((row >> 11) << 4) + (col >> 6)) * 131072 + (long)(col & 63) * 2048 + (row & 2047)] = (_Float16)v;
                } else if constexpr (OUT_MODE == 2) {
                    float* dst = (float*)Cp;
                    dst[(long)row * 1024 + col] = v;
                } else {
                    float* dst = (float*)Cp + (long)z * sCz;
                    dst[(long)row * 2048 + col] = v;
                }
            }
        }
    }
}

// In-place row softmax over the [65536, 2048] fp32 weights region.
__global__ __launch_bounds__(256) void softmax_rows(float* __restrict__ W)
{
    const long row = blockIdx.x;
    float* p = W + row * 2048;
    const int t = threadIdx.x;
    const int lane = t & 63, wave = t >> 6;

    float4 a = *(const float4*)(p + 4 * t);
    float4 b = *(const float4*)(p + 1024 + 4 * t);

    float m = fmaxf(fmaxf(fmaxf(a.x, a.y), fmaxf(a.z, a.w)),
                    fmaxf(fmaxf(b.x, b.y), fmaxf(b.z, b.w)));
#pragma unroll
    for (int off = 32; off > 0; off >>= 1) m = fmaxf(m, __shfl_xor(m, off));
    __shared__ float redm[4];
    if (lane == 0) redm[wave] = m;
    __syncthreads();
    m = fmaxf(fmaxf(redm[0], redm[1]), fmaxf(redm[2], redm[3]));

    a.x = __expf(a.x - m); a.y = __expf(a.y - m); a.z = __expf(a.z - m); a.w = __expf(a.w - m);
    b.x = __expf(b.x - m); b.y = __expf(b.y - m); b.z = __expf(b.z - m); b.w = __expf(b.w - m);
    float s = a.x + a.y + a.z + a.w + b.x + b.y + b.z + b.w;
#pragma unroll
    for (int off = 32; off > 0; off >>= 1) s += __shfl_xor(s, off);
    __shared__ float reds[4];
    if (lane == 0) reds[wave] = s;
    __syncthreads();
    s = reds[0] + reds[1] + reds[2] + reds[3];
    const float inv = 1.0f / s;

    a.x *= inv; a.y *= inv; a.z *= inv; a.w *= inv;
    b.x *= inv; b.y *= inv; b.z *= inv; b.w *= inv;
    *(float4*)(p + 4 * t) = a;
    *(float4*)(p + 1024 + 4 * t) = b;
}

// Z = W @ V  per (b,h): A = fp32 weights [2048,2048], B = Vt fp16 [64,2048] (BT form).
// Tile 128x64, 4 waves (each 32 rows x 64 cols), BK=32.
__global__ __launch_bounds__(256) void gemm_av(
    const float* __restrict__ Wgt, const _Float16* __restrict__ Vt, _Float16* __restrict__ Z)
{
    __shared__ __align__(16) _Float16 sA[128 * 32];
    __shared__ __align__(16) _Float16 sB[64 * 32];

    const int t = threadIdx.x;
    const int tileM = blockIdx.x * 128;
    const int z = blockIdx.y;
    const int bb = z >> 4, hd = z & 15;

    const int srow = t >> 1, shalf = t & 1, c0 = shalf * 2;
    const int brow = t >> 2, bch = t & 3;
    const int lane = t & 63, wave = t >> 6;
    const int l15 = lane & 15, quad = lane >> 4;

    const float* Asrc = Wgt + (long)z * 4194304;
    const _Float16* Bsrc = Vt + (long)z * 131072;

    floatx4 acc[2][4];
#pragma unroll
    for (int i = 0; i < 2; i++)
#pragma unroll
        for (int j = 0; j < 4; j++)
            acc[i][j] = (floatx4){0.f, 0.f, 0.f, 0.f};

    for (int k0 = 0; k0 < 2048; k0 += 32) {
        __syncthreads();
        {
            const float* src = Asrc + (long)(tileM + srow) * 2048 + k0 + shalf * 16;
            float fx[16];
            *(float4*)(fx + 0)  = *(const float4*)(src + 0);
            *(float4*)(fx + 4)  = *(const float4*)(src + 4);
            *(float4*)(fx + 8)  = *(const float4*)(src + 8);
            *(float4*)(fx + 12) = *(const float4*)(src + 12);
            half8 h0, h1;
#pragma unroll
            for (int i = 0; i < 8; i++) { h0[i] = (_Float16)fx[i]; h1[i] = (_Float16)fx[8 + i]; }
            *(half8*)&sA[lds_off(srow, c0)]     = h0;
            *(half8*)&sA[lds_off(srow, c0 + 1)] = h1;
        }
        *(half8*)&sB[lds_off(brow, bch)] = *(const half8*)(Bsrc + (long)brow * 2048 + k0 + bch * 8);
        __syncthreads();

        half8 af[2], bf[4];
#pragma unroll
        for (int i = 0; i < 2; i++) af[i] = *(const half8*)&sA[lds_off(wave * 32 + i * 16 + l15, quad)];
#pragma unroll
        for (int j = 0; j < 4; j++) bf[j] = *(const half8*)&sB[lds_off(j * 16 + l15, quad)];
#pragma unroll
        for (int i = 0; i < 2; i++)
#pragma unroll
            for (int j = 0; j < 4; j++)
                acc[i][j] = __builtin_amdgcn_mfma_f32_16x16x32_f16(af[i], bf[j], acc[i][j], 0, 0, 0);
    }

#pragma unroll
    for (int i = 0; i < 2; i++)
#pragma unroll
        for (int j = 0; j < 4; j++)
#pragma unroll
            for (int r = 0; r < 4; r++) {
                const int lrow = tileM + wave * 32 + i * 16 + quad * 4 + r;
                const int col = j * 16 + l15;
                Z[(long)(bb * 2048 + lrow) * 1024 + hd * 64 + col] = (_Float16)acc[i][j][r];
            }
}

extern "C" void kernel_launch(void* const* d_in, const int* in_sizes, int n_in,
                              void* d_out, int out_size, void* d_ws, size_t ws_size,
                              hipStream_t stream) {
    (void)in_sizes; (void)n_in; (void)out_size; (void)ws_size;
    const float* query = (const float*)d_in[0];
    const float* key   = (const float*)d_in[1];
    const float* value = (const float*)d_in[2];
    const float* Wq = (const float*)d_in[3];
    const float* bq = (const float*)d_in[4];
    const float* Wk = (const float*)d_in[5];
    const float* bk = (const float*)d_in[6];
    const float* Wv = (const float*)d_in[7];
    const float* bv = (const float*)d_in[8];
    const float* Wo = (const float*)d_in[9];
    const float* bo = (const float*)d_in[10];

    _Float16* wsQ  = (_Float16*)d_ws;        // [32][2048][64]
    _Float16* wsK  = wsQ + 4194304;          // [32][2048][64]
    _Float16* wsVt = wsK + 4194304;          // [32][64][2048]
    _Float16* wsZ  = wsVt + 4194304;         // [4096][1024]

    float* outF = (float*)d_out;             // [4096][1024]
    float* Wgt  = outF + 4194304;            // [32][2048][2048]

    dim3 blk(256);
    // Q/K/V projections (fp32 inputs converted during staging)
    gemm128<true, true, 0><<<dim3(8, 32, 1), blk, 0, stream>>>(query, 1024, 0, Wq, 1024, 0, bq, 1.0f, wsQ, 0, 1024);
    gemm128<true, true, 0><<<dim3(8, 32, 1), blk, 0, stream>>>(key,   1024, 0, Wk, 1024, 0, bk, 1.0f, wsK, 0, 1024);
    gemm128<true, true, 1><<<dim3(8, 32, 1), blk, 0, stream>>>(value, 1024, 0, Wv, 1024, 0, bv, 1.0f, wsVt, 0, 1024);
    // Scores: S = Q K^T / 8, per (b,h), written fp32 into the weights output region
    gemm128<false, false, 3><<<dim3(16, 16, 32), blk, 0, stream>>>(wsQ, 64, 131072, wsK, 64, 131072, nullptr, 0.125f, Wgt, 4194304, 64);
    // Row softmax in place
    softmax_rows<<<65536, 256, 0, stream>>>(Wgt);
    // Z = W V
    gemm_av<<<dim3(16, 32), blk, 0, stream>>>(Wgt, wsVt, wsZ);
    // out = Z Wo^T + bo
    gemm128<false, true, 2><<<dim3(8, 32, 1), blk, 0, stream>>>(wsZ, 1024, 0, Wo, 1024, 0, bo, 1.0f, outF, 0, 1024);
}